// Round 1
// 1213.639 us; speedup vs baseline: 1.1382x; 1.1382x over previous
//
#include <hip/hip_runtime.h>
#include <cstdint>
#include <cstddef>

#define HW 16384
#define NEGF (-__builtin_inff())

typedef unsigned short u16;
typedef _Float16 f16;
typedef _Float16 f16x8 __attribute__((ext_vector_type(8)));
typedef float f32x4 __attribute__((ext_vector_type(4)));

// monotone key: float -> unsigned, order-preserving (handles negatives)
__device__ __forceinline__ unsigned fkey(float f) {
  unsigned b = __float_as_uint(f);
  return (b & 0x80000000u) ? ~b : (b | 0x80000000u);
}
__device__ __forceinline__ float funkey(unsigned u) {
  unsigned b = (u & 0x80000000u) ? (u ^ 0x80000000u) : ~u;
  return __uint_as_float(b);
}

// bf16 <-> f32 (RNE), deterministic everywhere
__device__ __forceinline__ float b2f(u16 u) {
  union { unsigned v; float f; } x; x.v = ((unsigned)u) << 16; return x.f;
}
__device__ __forceinline__ u16 f2b(float f) {
  union { float f; unsigned v; } x; x.f = f;
  unsigned r = x.v + 0x7FFFu + ((x.v >> 16) & 1u);
  return (u16)(r >> 16);
}

// ---------------- pack weights: f16, MFMA-fragment order + biases ----------------
// Wp layout: [kchunk=8][ofrag=20][lane=64][j=8] halfs.
// element = W[o = ofrag*16 + (lane&15)][k = kchunk*32 + (lane>>4)*8 + j]
__global__ __launch_bounds__(256) void pack_kernel(
    const float* __restrict__ Wq, const float* __restrict__ bq,
    const float* __restrict__ Wk, const float* __restrict__ bk,
    const float* __restrict__ Wv, const float* __restrict__ bv,
    u16* __restrict__ Wp, float* __restrict__ ball)
{
  int i = blockIdx.x * 256 + threadIdx.x;   // 0..81919
  {
    int chunk = i / 10240;
    int r = i - chunk * 10240;
    int frag = r >> 9;
    int lane = (r >> 3) & 63;
    int j = i & 7;
    int o = frag * 16 + (lane & 15);
    int kk = chunk * 32 + (lane >> 4) * 8 + j;
    float wv_ = (o < 32) ? Wq[o * 256 + kk]
              : (o < 64) ? Wk[(o - 32) * 256 + kk]
                         : Wv[(o - 64) * 256 + kk];
    f16 h = (f16)wv_;
    Wp[i] = *(u16*)&h;
  }
  if (i < 320) {
    ball[i] = (i < 32) ? bq[i] : (i < 64) ? bk[i - 32] : bv[i - 64];
  }
}

// ---------------- projections via f16 MFMA: q,k (fp32), v (bf16) ----------------
// block: 64 px, all 320 outputs. 4 waves x (5 o-frags x 4 px-frags) 16x16 tiles.
// K-loop: 8 chunks of 32. W pre-packed frag-order (linear LDS, conflict-free reads);
// X reg-staged fp32->f16 into [px][k] tiles with XOR slot swizzle (bank-uniform).
__global__ __launch_bounds__(256) void proj_kernel(
    const float* __restrict__ x1, const float* __restrict__ x2,
    const u16* __restrict__ Wp, const float* __restrict__ ball,
    float* __restrict__ q, float* __restrict__ k, u16* __restrict__ v)
{
  __shared__ __align__(16) u16 wlds[10240];      // 20 KB: [ofrag][lane][8]
  __shared__ __align__(16) u16 xlds[2][2048];    // 2 x 4 KB: [px=64][k=32] swizzled
  const int t = threadIdx.x;
  const int w = t >> 6, l = t & 63;
  const int blk = blockIdx.x;
  const int b = blk >> 8;
  const int p0 = (blk & 255) << 6;

  // accumulators init with bias (bias depends on o only; row = (l>>4)*4 + r)
  f32x4 acc[5][4];
#pragma unroll
  for (int f = 0; f < 5; ++f) {
    f32x4 binit;
#pragma unroll
    for (int r = 0; r < 4; ++r)
      binit[r] = ball[(w * 5 + f) * 16 + (l >> 4) * 4 + r];
#pragma unroll
    for (int pf = 0; pf < 4; ++pf) acc[f][pf] = binit;
  }

  // X staging assignment: wave w -> matrix (w&1: 0=x1,1=x2), k-half (w>>1).
  // lane: px = 2*(l&31) (+1), k0 = (l>>5)*8 within the half.
  const float* xp = (w & 1) ? x2 : x1;
  const int ks_l = (w >> 1) * 16 + (l >> 5) * 8;
  const int px_w = (l & 31) * 2;
  char* xdst = (char*)&xlds[w & 1][0];
  const int kgw = ks_l >> 3;
  const int offA = px_w * 64 + ((kgw ^ (px_w & 3)) << 4);
  const int offB = (px_w + 1) * 64 + ((kgw ^ ((px_w + 1) & 3)) << 4);

  const int prow = l & 15, kg2 = l >> 4;
  const char* xsrc1 = (const char*)&xlds[0][0];
  const char* xsrc2 = (const char*)&xlds[1][0];

  for (int ch = 0; ch < 8; ++ch) {
    // ---- issue-early: global loads for this chunk (no LDS touch yet) ----
    int4 wreg[5];
#pragma unroll
    for (int r = 0; r < 5; ++r)
      wreg[r] = *(const int4*)((const char*)Wp + ch * 20480 + (r * 256 + t) * 16);
    float2 xv[8];
    {
      size_t gbase = ((size_t)(b * 256 + ch * 32 + ks_l)) * HW + p0 + px_w;
#pragma unroll
      for (int i = 0; i < 8; ++i) xv[i] = *(const float2*)&xp[gbase + (size_t)i * HW];
    }
    __syncthreads();   // previous chunk's LDS readers done
    // ---- write LDS ----
#pragma unroll
    for (int r = 0; r < 5; ++r)
      *(int4*)((char*)wlds + (r * 256 + t) * 16) = wreg[r];
    {
      union { u16 h[8]; int4 v4; } pk0, pk1;
#pragma unroll
      for (int i = 0; i < 8; ++i) {
        f16 a = (f16)xv[i].x, c = (f16)xv[i].y;
        pk0.h[i] = *(u16*)&a; pk1.h[i] = *(u16*)&c;
      }
      *(int4*)(xdst + offA) = pk0.v4;
      *(int4*)(xdst + offB) = pk1.v4;
    }
    __syncthreads();   // LDS tiles ready

    // ---- fragments + MFMA ----
    f16x8 af[5];
#pragma unroll
    for (int f = 0; f < 5; ++f)
      af[f] = *(const f16x8*)((const char*)wlds + (((w * 5 + f) * 64 + l) << 4));
    f16x8 bf[4];
#pragma unroll
    for (int pf = 0; pf < 4; ++pf) {
      int row = pf * 16 + prow;
      bf[pf] = *(const f16x8*)(xsrc2 + row * 64 + ((kg2 ^ (row & 3)) << 4));
    }
    if (w == 0) {
      // frags 2..4 (k, v0) use x2
#pragma unroll
      for (int f = 2; f < 5; ++f)
#pragma unroll
        for (int pf = 0; pf < 4; ++pf)
          acc[f][pf] = __builtin_amdgcn_mfma_f32_16x16x32_f16(af[f], bf[pf], acc[f][pf], 0, 0, 0);
      // frags 0,1 (q) use x1
#pragma unroll
      for (int pf = 0; pf < 4; ++pf) {
        int row = pf * 16 + prow;
        bf[pf] = *(const f16x8*)(xsrc1 + row * 64 + ((kg2 ^ (row & 3)) << 4));
      }
#pragma unroll
      for (int f = 0; f < 2; ++f)
#pragma unroll
        for (int pf = 0; pf < 4; ++pf)
          acc[f][pf] = __builtin_amdgcn_mfma_f32_16x16x32_f16(af[f], bf[pf], acc[f][pf], 0, 0, 0);
    } else {
#pragma unroll
      for (int f = 0; f < 5; ++f)
#pragma unroll
        for (int pf = 0; pf < 4; ++pf)
          acc[f][pf] = __builtin_amdgcn_mfma_f32_16x16x32_f16(af[f], bf[pf], acc[f][pf], 0, 0, 0);
    }
  }

  // ---- epilogue: C/D layout col(px)=l&15, row(o)=(l>>4)*4+reg ----
  const size_t pxb = (size_t)p0 + (l & 15);
#pragma unroll
  for (int f = 0; f < 5; ++f) {
    int of = w * 5 + f;
    if (of < 2) {
#pragma unroll
      for (int r = 0; r < 4; ++r) {
        int o = of * 16 + (l >> 4) * 4 + r;
        float* dst = q + ((size_t)b * 32 + o) * HW + pxb;
#pragma unroll
        for (int pf = 0; pf < 4; ++pf) dst[pf * 16] = acc[f][pf][r];
      }
    } else if (of < 4) {
#pragma unroll
      for (int r = 0; r < 4; ++r) {
        int o = (of - 2) * 16 + (l >> 4) * 4 + r;
        float* dst = k + ((size_t)b * 32 + o) * HW + pxb;
#pragma unroll
        for (int pf = 0; pf < 4; ++pf) dst[pf * 16] = acc[f][pf][r];
      }
    } else {
#pragma unroll
      for (int r = 0; r < 4; ++r) {
        int o = (of - 4) * 16 + (l >> 4) * 4 + r;
        u16* dst = v + ((size_t)b * 256 + o) * HW + pxb;
#pragma unroll
        for (int pf = 0; pf < 4; ++pf) dst[pf * 16] = f2b(acc[f][pf][r]);
      }
    }
  }
}

// ---------------- spatial transpose fp32 (per 128x128 plane) ----------------
__global__ __launch_bounds__(256) void transpose_f32(
    const float* __restrict__ in, float* __restrict__ out)
{
  __shared__ float s[32][33];
  const int plane = blockIdx.y;
  const int tw = blockIdx.x & 3, th = blockIdx.x >> 2;
  const float* ip = in + (size_t)plane * HW;
  float* op = out + (size_t)plane * HW;
  const int lx = threadIdx.x & 31, ly = threadIdx.x >> 5;
  const int r0 = th << 5, c0 = tw << 5;
#pragma unroll
  for (int r = 0; r < 4; ++r) s[ly + 8 * r][lx] = ip[(r0 + ly + 8 * r) * 128 + c0 + lx];
  __syncthreads();
#pragma unroll
  for (int r = 0; r < 4; ++r) op[(c0 + ly + 8 * r) * 128 + r0 + lx] = s[lx][ly + 8 * r];
}

// ---------------- spatial transpose bf16 ----------------
__global__ __launch_bounds__(256) void transpose_b16(
    const u16* __restrict__ in, u16* __restrict__ out)
{
  __shared__ u16 s[32][33];
  const int plane = blockIdx.y;
  const int tw = blockIdx.x & 3, th = blockIdx.x >> 2;
  const u16* ip = in + (size_t)plane * HW;
  u16* op = out + (size_t)plane * HW;
  const int lx = threadIdx.x & 31, ly = threadIdx.x >> 5;
  const int r0 = th << 5, c0 = tw << 5;
#pragma unroll
  for (int r = 0; r < 4; ++r) s[ly + 8 * r][lx] = ip[(r0 + ly + 8 * r) * 128 + c0 + lx];
  __syncthreads();
#pragma unroll
  for (int r = 0; r < 4; ++r) op[(c0 + ly + 8 * r) * 128 + r0 + lx] = s[lx][ly + 8 * r];
}

// out += gamma * bf16(in)^T (per plane)
__global__ __launch_bounds__(256) void addT_kernel(
    const u16* __restrict__ in, const float* __restrict__ gptr, float* __restrict__ out)
{
  __shared__ float s[32][33];
  const int plane = blockIdx.y;
  const int tw = blockIdx.x & 3, th = blockIdx.x >> 2;
  const float g = gptr[0];
  const u16* ip = in + (size_t)plane * HW;
  float* op = out + (size_t)plane * HW;
  const int lx = threadIdx.x & 31, ly = threadIdx.x >> 5;
  const int r0 = th << 5, c0 = tw << 5;
#pragma unroll
  for (int r = 0; r < 4; ++r) s[ly + 8 * r][lx] = b2f(ip[(r0 + ly + 8 * r) * 128 + c0 + lx]);
  __syncthreads();
#pragma unroll
  for (int r = 0; r < 4; ++r) {
    size_t o = (size_t)(c0 + ly + 8 * r) * 128 + r0 + lx;
    op[o] = op[o] + g * s[lx][ly + 8 * r];
  }
}

// ---------------- stats pass: exact top-64 threshold + (m, l) per row ----------------
// block = (po, b): po is w (column pass, via qT/kT) or h (row pass, via q/k)
__global__ __launch_bounds__(256) void stats_kernel(
    const float* __restrict__ qp, const float* __restrict__ kp,
    float* __restrict__ thr_out, float* __restrict__ m_out, float* __restrict__ l_out,
    int diag)
{
  __shared__ float q_s[32][128];
  __shared__ float k_s[32][132];
  __shared__ float e_s[32][132];
  const int t = threadIdx.x;
  const int po = blockIdx.x, b = blockIdx.y;

#pragma unroll
  for (int r = 0; r < 16; ++r) {
    int i = t + r * 256;
    int c = i >> 7, h = i & 127;
    size_t base = ((size_t)(b * 32 + c) * 128 + po) * 128;
    q_s[c][h] = qp[base + h];
    k_s[c][h] = kp[base + h];
  }
  __syncthreads();

  const int hh = t >> 3;
  const int gg0 = (t & 7) << 4;
  const int wv = t >> 6, ln = t & 63;

  for (int h0 = 0; h0 < 128; h0 += 32) {
    float acc[16];
#pragma unroll
    for (int j = 0; j < 16; ++j) acc[j] = 0.0f;
#pragma unroll
    for (int c = 0; c < 32; ++c) {
      float qv = q_s[c][h0 + hh];
      float4 kv[4];
      kv[0] = *(const float4*)&k_s[c][gg0];
      kv[1] = *(const float4*)&k_s[c][gg0 + 4];
      kv[2] = *(const float4*)&k_s[c][gg0 + 8];
      kv[3] = *(const float4*)&k_s[c][gg0 + 12];
#pragma unroll
      for (int j4 = 0; j4 < 4; ++j4) {
        acc[j4 * 4 + 0] = fmaf(qv, kv[j4].x, acc[j4 * 4 + 0]);
        acc[j4 * 4 + 1] = fmaf(qv, kv[j4].y, acc[j4 * 4 + 1]);
        acc[j4 * 4 + 2] = fmaf(qv, kv[j4].z, acc[j4 * 4 + 2]);
        acc[j4 * 4 + 3] = fmaf(qv, kv[j4].w, acc[j4 * 4 + 3]);
      }
    }
    if (diag) {
      int h = h0 + hh;
#pragma unroll
      for (int j = 0; j < 16; ++j)
        if (gg0 + j == h) acc[j] = NEGF;
    }
#pragma unroll
    for (int j4 = 0; j4 < 4; ++j4)
      *(float4*)&e_s[hh][gg0 + j4 * 4] =
          make_float4(acc[j4 * 4 + 0], acc[j4 * 4 + 1], acc[j4 * 4 + 2], acc[j4 * 4 + 3]);
    __syncthreads();

    for (int rr = 0; rr < 8; ++rr) {
      int row = wv * 8 + rr;
      float e0 = e_s[row][ln], e1 = e_s[row][ln + 64];
      unsigned u0 = fkey(e0), u1 = fkey(e1);
      // exact 64th-largest via bitwise binary search over order-preserving keys
      unsigned uthr = 0u;
      for (int bit = 31; bit >= 0; --bit) {
        unsigned cand = uthr | (1u << bit);
        int cnt = __popcll(__ballot(u0 >= cand)) + __popcll(__ballot(u1 >= cand));
        if (cnt >= 64) uthr = cand;
      }
      unsigned um = u0 > u1 ? u0 : u1;
#pragma unroll
      for (int off = 32; off; off >>= 1) {
        unsigned o = __shfl_xor(um, off);
        um = um > o ? um : o;
      }
      float m = funkey(um);
      float s = ((u0 >= uthr) ? __expf(e0 - m) : 0.0f) +
                ((u1 >= uthr) ? __expf(e1 - m) : 0.0f);
#pragma unroll
      for (int off = 32; off; off >>= 1) s += __shfl_xor(s, off);
      if (ln == 0) {
        size_t idx = ((size_t)b * 128 + po) * 128 + h0 + row;
        thr_out[idx] = __uint_as_float(uthr);
        m_out[idx] = m;
        l_out[idx] = s;
      }
    }
    __syncthreads();
  }
}

// ---------------- output pass: out[c][i] = sum_j v[c][j] * att[i][j] ----------------
// block = (i-tile of 32, po, b); thread t = channel c; recomputes e bit-identically
// FUSE=1: writes fp32 out with gamma*acc + x1.  FUSE=0: writes bf16 accH.
template <int DIAG, int FUSE>
__global__ __launch_bounds__(256) void out_kernel(
    const float* __restrict__ qp, const float* __restrict__ kp, const u16* __restrict__ vp,
    const float* __restrict__ thr_own, const float* __restrict__ m_own, const float* __restrict__ l_own,
    const float* __restrict__ m_oth, const float* __restrict__ l_oth,
    const float* __restrict__ x1, const float* __restrict__ gptr,
    void* __restrict__ outp_v)
{
  __shared__ float q_s[32][36];
  __shared__ float k_s[32][132];
  __shared__ float att_s[32][36];   // [j][i]
  __shared__ float m_s[32], il_s[32];
  __shared__ unsigned ut_s[32];
  const int t = threadIdx.x;
  const int i0 = blockIdx.x << 5;
  const int po = blockIdx.y, b = blockIdx.z;

  {
    int c = t >> 3, ii4 = (t & 7) << 2;
    size_t base = ((size_t)(b * 32 + c) * 128 + po) * 128 + i0 + ii4;
    *(float4*)&q_s[c][ii4] = *(const float4*)&qp[base];
  }
#pragma unroll
  for (int r = 0; r < 4; ++r) {
    int i = t + r * 256;
    int c = i >> 5, g4 = (i & 31) << 2;
    *(float4*)&k_s[c][g4] = *(const float4*)&kp[((size_t)(b * 32 + c) * 128 + po) * 128 + g4];
  }
  if (t < 32) {
    size_t own = ((size_t)b * 128 + po) * 128 + i0 + t;
    size_t oth = ((size_t)b * 128 + i0 + t) * 128 + po;
    float ma = m_own[own], la = l_own[own];
    float mb = m_oth[oth], lb = l_oth[oth];
    float m = fmaxf(ma, mb);
    float l = la * __expf(ma - m) + lb * __expf(mb - m);
    m_s[t] = m;
    il_s[t] = 1.0f / l;
    ut_s[t] = __float_as_uint(thr_own[own]);
  }

  float acc[32];
#pragma unroll
  for (int i = 0; i < 32; ++i) acc[i] = 0.0f;

  const int ii = t & 31;
  const int j0 = (t >> 5) << 2;

  for (int gc = 0; gc < 4; ++gc) {
    float vr[32];
    {
      size_t base = ((size_t)(b * 256 + t) * 128 + po) * 128 + gc * 32;
#pragma unroll
      for (int j4 = 0; j4 < 8; ++j4) {
        ushort4 tmp = *(const ushort4*)&vp[base + j4 * 4];
        vr[j4 * 4 + 0] = b2f(tmp.x); vr[j4 * 4 + 1] = b2f(tmp.y);
        vr[j4 * 4 + 2] = b2f(tmp.z); vr[j4 * 4 + 3] = b2f(tmp.w);
      }
    }
    __syncthreads();   // gc=0: fills+stats ready; gc>0: att_s consumers done
    {
      float e[4] = {0.0f, 0.0f, 0.0f, 0.0f};
#pragma unroll
      for (int c = 0; c < 32; ++c) {
        float qv = q_s[c][ii];
        float4 kv = *(const float4*)&k_s[c][gc * 32 + j0];
        e[0] = fmaf(qv, kv.x, e[0]);
        e[1] = fmaf(qv, kv.y, e[1]);
        e[2] = fmaf(qv, kv.z, e[2]);
        e[3] = fmaf(qv, kv.w, e[3]);
      }
#pragma unroll
      for (int jj = 0; jj < 4; ++jj) {
        float a;
        int jg = gc * 32 + j0 + jj;
        if (DIAG && jg == i0 + ii) {
          a = 0.0f;
        } else {
          unsigned ue = fkey(e[jj]);
          a = (ue >= ut_s[ii]) ? __expf(e[jj] - m_s[ii]) * il_s[ii] : 0.0f;
        }
        att_s[j0 + jj][ii] = a;
      }
    }
    __syncthreads();
#pragma unroll
    for (int j = 0; j < 32; ++j) {
      float vv = vr[j];
#pragma unroll
      for (int i4 = 0; i4 < 8; ++i4) {
        float4 a = *(const float4*)&att_s[j][i4 * 4];
        acc[i4 * 4 + 0] = fmaf(vv, a.x, acc[i4 * 4 + 0]);
        acc[i4 * 4 + 1] = fmaf(vv, a.y, acc[i4 * 4 + 1]);
        acc[i4 * 4 + 2] = fmaf(vv, a.z, acc[i4 * 4 + 2]);
        acc[i4 * 4 + 3] = fmaf(vv, a.w, acc[i4 * 4 + 3]);
      }
    }
  }

  size_t obase = ((size_t)(b * 256 + t) * 128 + po) * 128 + i0;
  if (FUSE) {
    const float g = gptr[0];
    float* outp = (float*)outp_v;
#pragma unroll
    for (int i4 = 0; i4 < 8; ++i4) {
      float4 xv = *(const float4*)&x1[obase + i4 * 4];
      float4 o;
      o.x = g * acc[i4 * 4 + 0] + xv.x;
      o.y = g * acc[i4 * 4 + 1] + xv.y;
      o.z = g * acc[i4 * 4 + 2] + xv.z;
      o.w = g * acc[i4 * 4 + 3] + xv.w;
      *(float4*)&outp[obase + i4 * 4] = o;
    }
  } else {
    u16* outp = (u16*)outp_v;
#pragma unroll
    for (int i4 = 0; i4 < 8; ++i4) {
      ushort4 o;
      o.x = f2b(acc[i4 * 4 + 0]); o.y = f2b(acc[i4 * 4 + 1]);
      o.z = f2b(acc[i4 * 4 + 2]); o.w = f2b(acc[i4 * 4 + 3]);
      *(ushort4*)&outp[obase + i4 * 4] = o;
    }
  }
}

// ---------------- launch ----------------
// ws budget (bytes): Wp f16 163,840 + ball | q,k,qT,kT fp32 67,108,864
// | stats 3,145,728 | v bf16 67,108,864 | vT bf16 67,108,864  => ~204.8 MB total.
// accH (bf16) aliases v: the W-pass out_kernel is the last reader of v and runs
// before the H-pass out_kernel writes accH.
extern "C" void kernel_launch(void* const* d_in, const int* in_sizes, int n_in,
                              void* d_out, int out_size, void* d_ws, size_t ws_size,
                              hipStream_t stream)
{
  const float* x1 = (const float*)d_in[0];
  const float* x2 = (const float*)d_in[1];
  const float* Wq = (const float*)d_in[2];
  const float* bq = (const float*)d_in[3];
  const float* Wk = (const float*)d_in[4];
  const float* bk = (const float*)d_in[5];
  const float* Wv = (const float*)d_in[6];
  const float* bv = (const float*)d_in[7];
  const float* gm = (const float*)d_in[8];
  float* out = (float*)d_out;
  float* ws = (float*)d_ws;

  u16*   Wp    = (u16*)ws;                // 81,920 halfs (= 40,960 f slots)
  float* ball  = ws + 81920;              // 320 f (region padded to 82,304)
  float* q     = ws + 82304;              // 4,194,304 f
  float* k     = q + 4194304;
  float* qT    = k + 4194304;
  float* kT    = qT + 4194304;
  float* stats = kT + 4194304;            // 786,432 f
  u16*   v     = (u16*)(stats + 786432);  // 33,554,432 bf16
  u16*   vT    = v + 33554432;            // 33,554,432 bf16
  u16*   accH  = v;                       // alias (v dead after W out pass)

  float* thrH = stats;
  float* mH   = stats + 131072;
  float* lH   = stats + 262144;
  float* thrW = stats + 393216;
  float* mW   = stats + 524288;
  float* lW   = stats + 655360;

  pack_kernel<<<320, 256, 0, stream>>>(Wq, bq, Wk, bk, Wv, bv, Wp, ball);
  proj_kernel<<<2048, 256, 0, stream>>>(x1, x2, Wp, ball, q, k, v);
  transpose_f32<<<dim3(16, 256), 256, 0, stream>>>(q, qT);
  transpose_f32<<<dim3(16, 256), 256, 0, stream>>>(k, kT);
  transpose_b16<<<dim3(16, 2048), 256, 0, stream>>>(v, vT);
  stats_kernel<<<dim3(128, 8), 256, 0, stream>>>(qT, kT, thrH, mH, lH, 1);
  stats_kernel<<<dim3(128, 8), 256, 0, stream>>>(q, k, thrW, mW, lW, 0);
  // W pass first (last reader of v), fused with gamma & +x1 into out:
  out_kernel<0, 1><<<dim3(4, 128, 8), 256, 0, stream>>>(
      q, k, v, thrW, mW, lW, mH, lH, x1, gm, (void*)out);
  // H pass writes transposed accumulator into the (now dead) v region:
  out_kernel<1, 0><<<dim3(4, 128, 8), 256, 0, stream>>>(
      qT, kT, vT, thrH, mH, lH, mW, lW, x1, gm, (void*)accH);
  addT_kernel<<<dim3(16, 2048), 256, 0, stream>>>(accH, gm, out);
}

// Round 2
// 828.422 us; speedup vs baseline: 1.6675x; 1.4650x over previous
//
#include <hip/hip_runtime.h>
#include <cstdint>
#include <cstddef>

#define HW 16384
#define NEGF (-__builtin_inff())

typedef unsigned short u16;
typedef _Float16 f16;
typedef _Float16 f16x8 __attribute__((ext_vector_type(8)));
typedef float f32x4 __attribute__((ext_vector_type(4)));

// monotone key: float -> unsigned, order-preserving (handles negatives)
__device__ __forceinline__ unsigned fkey(float f) {
  unsigned b = __float_as_uint(f);
  return (b & 0x80000000u) ? ~b : (b | 0x80000000u);
}
__device__ __forceinline__ float funkey(unsigned u) {
  unsigned b = (u & 0x80000000u) ? (u ^ 0x80000000u) : ~u;
  return __uint_as_float(b);
}

// f16 <-> f32
__device__ __forceinline__ float h2f(u16 u) { f16 h; *(u16*)&h = u; return (float)h; }
__device__ __forceinline__ u16 f2h(float f) { f16 h = (f16)f; return *(u16*)&h; }

union i4h8 { int4 i; f16x8 h; };

// ---------------- pack weights: f16, MFMA-fragment order + biases ----------------
// Wp layout: [kchunk=8][ofrag=20][lane=64][j=8] halfs.
// element = W[o = ofrag*16 + (lane&15)][k = kchunk*32 + (lane>>4)*8 + j]
__global__ __launch_bounds__(256) void pack_kernel(
    const float* __restrict__ Wq, const float* __restrict__ bq,
    const float* __restrict__ Wk, const float* __restrict__ bk,
    const float* __restrict__ Wv, const float* __restrict__ bv,
    u16* __restrict__ Wp, float* __restrict__ ball)
{
  int i = blockIdx.x * 256 + threadIdx.x;   // 0..81919
  {
    int chunk = i / 10240;
    int r = i - chunk * 10240;
    int frag = r >> 9;
    int lane = (r >> 3) & 63;
    int j = i & 7;
    int o = frag * 16 + (lane & 15);
    int kk = chunk * 32 + (lane >> 4) * 8 + j;
    float wv_ = (o < 32) ? Wq[o * 256 + kk]
              : (o < 64) ? Wk[(o - 32) * 256 + kk]
                         : Wv[(o - 64) * 256 + kk];
    Wp[i] = f2h(wv_);
  }
  if (i < 320) {
    ball[i] = (i < 32) ? bq[i] : (i < 64) ? bk[i - 32] : bv[i - 64];
  }
}

// ---------------- projections via f16 MFMA ----------------
// outputs: q16,k16 = f16 NHWC [b][p][32c]; v = f16 planar [b][c][p]
__global__ __launch_bounds__(256) void proj_kernel(
    const float* __restrict__ x1, const float* __restrict__ x2,
    const u16* __restrict__ Wp, const float* __restrict__ ball,
    u16* __restrict__ q16, u16* __restrict__ k16, u16* __restrict__ v)
{
  __shared__ __align__(16) u16 wlds[10240];      // 20 KB: [ofrag][lane][8]
  __shared__ __align__(16) u16 xlds[2][2048];    // 2 x 4 KB: [px=64][k=32] swizzled
  const int t = threadIdx.x;
  const int w = t >> 6, l = t & 63;
  const int blk = blockIdx.x;
  const int b = blk >> 8;
  const int p0 = (blk & 255) << 6;

  // accumulators init with bias (bias depends on o only; row = (l>>4)*4 + r)
  f32x4 acc[5][4];
#pragma unroll
  for (int f = 0; f < 5; ++f) {
    f32x4 binit;
#pragma unroll
    for (int r = 0; r < 4; ++r)
      binit[r] = ball[(w * 5 + f) * 16 + (l >> 4) * 4 + r];
#pragma unroll
    for (int pf = 0; pf < 4; ++pf) acc[f][pf] = binit;
  }

  const float* xp = (w & 1) ? x2 : x1;
  const int ks_l = (w >> 1) * 16 + (l >> 5) * 8;
  const int px_w = (l & 31) * 2;
  char* xdst = (char*)&xlds[w & 1][0];
  const int kgw = ks_l >> 3;
  const int offA = px_w * 64 + ((kgw ^ (px_w & 3)) << 4);
  const int offB = (px_w + 1) * 64 + ((kgw ^ ((px_w + 1) & 3)) << 4);

  const int prow = l & 15, kg2 = l >> 4;
  const char* xsrc1 = (const char*)&xlds[0][0];
  const char* xsrc2 = (const char*)&xlds[1][0];

  for (int ch = 0; ch < 8; ++ch) {
    int4 wreg[5];
#pragma unroll
    for (int r = 0; r < 5; ++r)
      wreg[r] = *(const int4*)((const char*)Wp + ch * 20480 + (r * 256 + t) * 16);
    float2 xv[8];
    {
      size_t gbase = ((size_t)(b * 256 + ch * 32 + ks_l)) * HW + p0 + px_w;
#pragma unroll
      for (int i = 0; i < 8; ++i) xv[i] = *(const float2*)&xp[gbase + (size_t)i * HW];
    }
    __syncthreads();
#pragma unroll
    for (int r = 0; r < 5; ++r)
      *(int4*)((char*)wlds + (r * 256 + t) * 16) = wreg[r];
    {
      union { u16 h[8]; int4 v4; } pk0, pk1;
#pragma unroll
      for (int i = 0; i < 8; ++i) {
        pk0.h[i] = f2h(xv[i].x); pk1.h[i] = f2h(xv[i].y);
      }
      *(int4*)(xdst + offA) = pk0.v4;
      *(int4*)(xdst + offB) = pk1.v4;
    }
    __syncthreads();

    f16x8 af[5];
#pragma unroll
    for (int f = 0; f < 5; ++f)
      af[f] = *(const f16x8*)((const char*)wlds + (((w * 5 + f) * 64 + l) << 4));
    f16x8 bf[4];
#pragma unroll
    for (int pf = 0; pf < 4; ++pf) {
      int row = pf * 16 + prow;
      bf[pf] = *(const f16x8*)(xsrc2 + row * 64 + ((kg2 ^ (row & 3)) << 4));
    }
    if (w == 0) {
#pragma unroll
      for (int f = 2; f < 5; ++f)
#pragma unroll
        for (int pf = 0; pf < 4; ++pf)
          acc[f][pf] = __builtin_amdgcn_mfma_f32_16x16x32_f16(af[f], bf[pf], acc[f][pf], 0, 0, 0);
#pragma unroll
      for (int pf = 0; pf < 4; ++pf) {
        int row = pf * 16 + prow;
        bf[pf] = *(const f16x8*)(xsrc1 + row * 64 + ((kg2 ^ (row & 3)) << 4));
      }
#pragma unroll
      for (int f = 0; f < 2; ++f)
#pragma unroll
        for (int pf = 0; pf < 4; ++pf)
          acc[f][pf] = __builtin_amdgcn_mfma_f32_16x16x32_f16(af[f], bf[pf], acc[f][pf], 0, 0, 0);
    } else {
#pragma unroll
      for (int f = 0; f < 5; ++f)
#pragma unroll
        for (int pf = 0; pf < 4; ++pf)
          acc[f][pf] = __builtin_amdgcn_mfma_f32_16x16x32_f16(af[f], bf[pf], acc[f][pf], 0, 0, 0);
    }
  }

  // ---- epilogue: C/D layout col(px)=l&15, row(o)=(l>>4)*4+r ----
#pragma unroll
  for (int f = 0; f < 5; ++f) {
    int of = w * 5 + f;
    if (of < 4) {
      // q16 (of 0,1) / k16 (of 2,3): NHWC f16, pack 4 consecutive o per store
      u16* dst16 = (of < 2) ? q16 : k16;
      int o = (of & 1) * 16 + (l >> 4) * 4;
#pragma unroll
      for (int pf = 0; pf < 4; ++pf) {
        int px = p0 + pf * 16 + (l & 15);
        ushort4 h4;
        h4.x = f2h(acc[f][pf][0]);
        h4.y = f2h(acc[f][pf][1]);
        h4.z = f2h(acc[f][pf][2]);
        h4.w = f2h(acc[f][pf][3]);
        *(ushort4*)&dst16[((size_t)b * HW + px) * 32 + o] = h4;
      }
    } else {
#pragma unroll
      for (int r = 0; r < 4; ++r) {
        int o = (of - 4) * 16 + (l >> 4) * 4 + r;
        u16* dst = v + ((size_t)b * 256 + o) * HW + (size_t)p0 + (l & 15);
#pragma unroll
        for (int pf = 0; pf < 4; ++pf) dst[pf * 16] = f2h(acc[f][pf][r]);
      }
    }
  }
}

// ---------------- spatial transpose 16-bit planar (per 128x128 plane) ----------------
__global__ __launch_bounds__(256) void transpose_b16(
    const u16* __restrict__ in, u16* __restrict__ out)
{
  __shared__ u16 s[32][33];
  const int plane = blockIdx.y;
  const int tw = blockIdx.x & 3, th = blockIdx.x >> 2;
  const u16* ip = in + (size_t)plane * HW;
  u16* op = out + (size_t)plane * HW;
  const int lx = threadIdx.x & 31, ly = threadIdx.x >> 5;
  const int r0 = th << 5, c0 = tw << 5;
#pragma unroll
  for (int r = 0; r < 4; ++r) s[ly + 8 * r][lx] = ip[(r0 + ly + 8 * r) * 128 + c0 + lx];
  __syncthreads();
#pragma unroll
  for (int r = 0; r < 4; ++r) op[(c0 + ly + 8 * r) * 128 + r0 + lx] = s[lx][ly + 8 * r];
}

// ---------------- NHWC 64B-granule spatial transpose: [b][h][w][32] -> [b][w][h][32] ----
__global__ __launch_bounds__(256) void transpose_c32(
    const u16* __restrict__ in, u16* __restrict__ out)
{
  const int b = blockIdx.y;
  const int tw = blockIdx.x & 7, th = blockIdx.x >> 3;
  const int lw = threadIdx.x & 15, lh = threadIdx.x >> 4;
  const int h = th * 16 + lh, wc = tw * 16 + lw;
  const u16* src = in + ((size_t)b * HW + h * 128 + wc) * 32;
  u16* dst = out + ((size_t)b * HW + wc * 128 + h) * 32;
  int4 v0 = *(const int4*)&src[0];
  int4 v1 = *(const int4*)&src[8];
  int4 v2 = *(const int4*)&src[16];
  int4 v3 = *(const int4*)&src[24];
  *(int4*)&dst[0] = v0;  *(int4*)&dst[8] = v1;
  *(int4*)&dst[16] = v2; *(int4*)&dst[24] = v3;
}

// out += gamma * f16(in)^T (per plane)
__global__ __launch_bounds__(256) void addT_kernel(
    const u16* __restrict__ in, const float* __restrict__ gptr, float* __restrict__ out)
{
  __shared__ float s[32][33];
  const int plane = blockIdx.y;
  const int tw = blockIdx.x & 3, th = blockIdx.x >> 2;
  const float g = gptr[0];
  const u16* ip = in + (size_t)plane * HW;
  float* op = out + (size_t)plane * HW;
  const int lx = threadIdx.x & 31, ly = threadIdx.x >> 5;
  const int r0 = th << 5, c0 = tw << 5;
#pragma unroll
  for (int r = 0; r < 4; ++r) s[ly + 8 * r][lx] = h2f(ip[(r0 + ly + 8 * r) * 128 + c0 + lx]);
  __syncthreads();
#pragma unroll
  for (int r = 0; r < 4; ++r) {
    size_t o = (size_t)(c0 + ly + 8 * r) * 128 + r0 + lx;
    op[o] = op[o] + g * s[lx][ly + 8 * r];
  }
}

// ---------------- stats pass: exact top-64 threshold + (m, l) per row ----------------
// inputs now f16 NHWC tiles: qp/kp = [b][po][row][32c], 8KB per (b,po)
__global__ __launch_bounds__(256) void stats_kernel(
    const u16* __restrict__ qp, const u16* __restrict__ kp,
    float* __restrict__ thr_out, float* __restrict__ m_out, float* __restrict__ l_out,
    int diag)
{
  __shared__ float q_s[32][132];
  __shared__ float k_s[32][132];
  __shared__ float e_s[32][132];
  const int t = threadIdx.x;
  const int po = blockIdx.x, b = blockIdx.y;

  const u16* qt = qp + (size_t)(b * 128 + po) * 128 * 32;
  const u16* kt = kp + (size_t)(b * 128 + po) * 128 * 32;
#pragma unroll
  for (int r = 0; r < 2; ++r) {
    int idx = t * 8 + r * 2048;          // pixel-major: idx = h*32 + c
    int h = idx >> 5, c0 = idx & 31;
    i4h8 qv; qv.i = *(const int4*)&qt[idx];
    i4h8 kv; kv.i = *(const int4*)&kt[idx];
#pragma unroll
    for (int j = 0; j < 8; ++j) {
      q_s[c0 + j][h] = (float)qv.h[j];
      k_s[c0 + j][h] = (float)kv.h[j];
    }
  }
  __syncthreads();

  const int hh = t >> 3;
  const int gg0 = (t & 7) << 4;
  const int wv = t >> 6, ln = t & 63;

  for (int h0 = 0; h0 < 128; h0 += 32) {
    float acc[16];
#pragma unroll
    for (int j = 0; j < 16; ++j) acc[j] = 0.0f;
#pragma unroll
    for (int c = 0; c < 32; ++c) {
      float qv = q_s[c][h0 + hh];
      float4 kv[4];
      kv[0] = *(const float4*)&k_s[c][gg0];
      kv[1] = *(const float4*)&k_s[c][gg0 + 4];
      kv[2] = *(const float4*)&k_s[c][gg0 + 8];
      kv[3] = *(const float4*)&k_s[c][gg0 + 12];
#pragma unroll
      for (int j4 = 0; j4 < 4; ++j4) {
        acc[j4 * 4 + 0] = fmaf(qv, kv[j4].x, acc[j4 * 4 + 0]);
        acc[j4 * 4 + 1] = fmaf(qv, kv[j4].y, acc[j4 * 4 + 1]);
        acc[j4 * 4 + 2] = fmaf(qv, kv[j4].z, acc[j4 * 4 + 2]);
        acc[j4 * 4 + 3] = fmaf(qv, kv[j4].w, acc[j4 * 4 + 3]);
      }
    }
    if (diag) {
      int h = h0 + hh;
#pragma unroll
      for (int j = 0; j < 16; ++j)
        if (gg0 + j == h) acc[j] = NEGF;
    }
#pragma unroll
    for (int j4 = 0; j4 < 4; ++j4)
      *(float4*)&e_s[hh][gg0 + j4 * 4] =
          make_float4(acc[j4 * 4 + 0], acc[j4 * 4 + 1], acc[j4 * 4 + 2], acc[j4 * 4 + 3]);
    __syncthreads();

    for (int rr = 0; rr < 8; ++rr) {
      int row = wv * 8 + rr;
      float e0 = e_s[row][ln], e1 = e_s[row][ln + 64];
      unsigned u0 = fkey(e0), u1 = fkey(e1);
      unsigned uthr = 0u;
      for (int bit = 31; bit >= 0; --bit) {
        unsigned cand = uthr | (1u << bit);
        int cnt = __popcll(__ballot(u0 >= cand)) + __popcll(__ballot(u1 >= cand));
        if (cnt >= 64) uthr = cand;
      }
      unsigned um = u0 > u1 ? u0 : u1;
#pragma unroll
      for (int off = 32; off; off >>= 1) {
        unsigned o = __shfl_xor(um, off);
        um = um > o ? um : o;
      }
      float m = funkey(um);
      float s = ((u0 >= uthr) ? __expf(e0 - m) : 0.0f) +
                ((u1 >= uthr) ? __expf(e1 - m) : 0.0f);
#pragma unroll
      for (int off = 32; off; off >>= 1) s += __shfl_xor(s, off);
      if (ln == 0) {
        size_t idx = ((size_t)b * 128 + po) * 128 + h0 + row;
        thr_out[idx] = __uint_as_float(uthr);
        m_out[idx] = m;
        l_out[idx] = s;
      }
    }
    __syncthreads();
  }
}

// ---------------- fused output pass, MFMA ----------------
// block = (po, b), 512 threads (8 waves). Phase 1: E = q k^T (K=32) per wave-i-frag.
// Phase 1.5: threshold/exp -> att f16 into swizzled LDS. Phase 2: out = att x V
// (V B-frags direct from global, prefetched at kernel start).
template <int DIAG, int FUSE>
__global__ __launch_bounds__(512) void out_mfma(
    const u16* __restrict__ q16, const u16* __restrict__ k16, const u16* __restrict__ vp,
    const float* __restrict__ thr_own, const float* __restrict__ m_own, const float* __restrict__ l_own,
    const float* __restrict__ m_oth, const float* __restrict__ l_oth,
    const float* __restrict__ x1, const float* __restrict__ gptr,
    void* __restrict__ outp_v)
{
  __shared__ __align__(16) u16 q_s[128 * 32];     // [i][c] 8KB
  __shared__ __align__(16) u16 k_s[128 * 32];     // [j][c] 8KB
  __shared__ __align__(16) u16 att_s[128 * 128];  // [i][16 swizzled 8-half slots] 32KB
  __shared__ float m_s[128], il_s[128];
  __shared__ unsigned ut_s[128];

  const int t = threadIdx.x;
  const int w = t >> 6, l = t & 63;
  const int l15 = l & 15, l4 = l >> 4;
  const int po = blockIdx.x, b = blockIdx.y;

  // ---- prefetch V B-fragments: c = w*32 + nf*16 + l15, j = ks*32 + l4*8 ----
  int4 vld[2][4];
#pragma unroll
  for (int nf = 0; nf < 2; ++nf) {
    int c = w * 32 + nf * 16 + l15;
    size_t vb = ((size_t)(b * 256 + c) * 128 + po) * 128 + l4 * 8;
#pragma unroll
    for (int ks = 0; ks < 4; ++ks)
      vld[nf][ks] = *(const int4*)&vp[vb + ks * 32];
  }

  // ---- stage q,k tiles (8KB each, 512 x 16B) ----
  {
    const u16* qt = q16 + (size_t)(b * 128 + po) * 128 * 32;
    const u16* kt = k16 + (size_t)(b * 128 + po) * 128 * 32;
    *(int4*)&q_s[t * 8] = *(const int4*)&qt[t * 8];
    *(int4*)&k_s[t * 8] = *(const int4*)&kt[t * 8];
  }
  // ---- combine stats ----
  if (t < 128) {
    size_t own = ((size_t)b * 128 + po) * 128 + t;
    size_t oth = ((size_t)b * 128 + t) * 128 + po;
    float ma = m_own[own], la = l_own[own];
    float mb = m_oth[oth], lb = l_oth[oth];
    float m = fmaxf(ma, mb);
    float lsum = la * __expf(ma - m) + lb * __expf(mb - m);
    m_s[t] = m;
    il_s[t] = 1.0f / lsum;
    ut_s[t] = __float_as_uint(thr_own[own]);
  }
  __syncthreads();

  // ---- phase 1: E rows i in [w*16, w*16+16) ----
  f32x4 eacc[8];
#pragma unroll
  for (int nj = 0; nj < 8; ++nj) eacc[nj] = (f32x4){0.f, 0.f, 0.f, 0.f};
  {
    f16x8 aq = *(const f16x8*)&q_s[(w * 16 + l15) * 32 + l4 * 8];
#pragma unroll
    for (int nj = 0; nj < 8; ++nj) {
      f16x8 bk = *(const f16x8*)&k_s[(nj * 16 + l15) * 32 + l4 * 8];
      eacc[nj] = __builtin_amdgcn_mfma_f32_16x16x32_f16(aq, bk, eacc[nj], 0, 0, 0);
    }
  }

  // ---- phase 1.5: threshold/exp -> att f16 (swizzled: slot = (j>>3) ^ (i&15)) ----
  {
    float mm[4], ii[4];
    unsigned uu[4];
#pragma unroll
    for (int r = 0; r < 4; ++r) {
      int i = w * 16 + l4 * 4 + r;
      mm[r] = m_s[i]; ii[r] = il_s[i]; uu[r] = ut_s[i];
    }
#pragma unroll
    for (int nj = 0; nj < 8; ++nj) {
      int j = nj * 16 + l15;
#pragma unroll
      for (int r = 0; r < 4; ++r) {
        int i = w * 16 + l4 * 4 + r;
        float e = eacc[nj][r];
        float a;
        if (DIAG && i == j) {
          a = 0.0f;
        } else {
          unsigned ue = fkey(e);
          a = (ue >= uu[r]) ? __expf(e - mm[r]) * ii[r] : 0.0f;
        }
        att_s[i * 128 + ((((j >> 3) ^ (i & 15)) << 3) | (j & 7))] = f2h(a);
      }
    }
  }
  __syncthreads();

  // ---- phase 2: out[i][c] = sum_j att[i][j] V[c][j]; wave owns 32 c ----
  f32x4 acc[8][2];
#pragma unroll
  for (int mi = 0; mi < 8; ++mi)
#pragma unroll
    for (int nf = 0; nf < 2; ++nf) acc[mi][nf] = (f32x4){0.f, 0.f, 0.f, 0.f};

#pragma unroll
  for (int ks = 0; ks < 4; ++ks) {
    i4h8 bv0, bv1;
    bv0.i = vld[0][ks];
    bv1.i = vld[1][ks];
#pragma unroll
    for (int mi = 0; mi < 8; ++mi) {
      int i = mi * 16 + l15;
      int s = (ks * 4 + l4) ^ (i & 15);
      f16x8 pa = *(const f16x8*)&att_s[i * 128 + s * 8];
      acc[mi][0] = __builtin_amdgcn_mfma_f32_16x16x32_f16(pa, bv0.h, acc[mi][0], 0, 0, 0);
      acc[mi][1] = __builtin_amdgcn_mfma_f32_16x16x32_f16(pa, bv1.h, acc[mi][1], 0, 0, 0);
    }
  }

  // ---- epilogue: D col = c (l15), row = i (l4*4 + r) ----
  const float g = gptr[0];
#pragma unroll
  for (int mi = 0; mi < 8; ++mi) {
#pragma unroll
    for (int nf = 0; nf < 2; ++nf) {
      int c = w * 32 + nf * 16 + l15;
      int i = mi * 16 + l4 * 4;
      size_t ob = ((size_t)(b * 256 + c) * 128 + po) * 128 + i;
      if (FUSE) {
        float* outp = (float*)outp_v;
        float4 xv = *(const float4*)&x1[ob];
        float4 o;
        o.x = g * acc[mi][nf][0] + xv.x;
        o.y = g * acc[mi][nf][1] + xv.y;
        o.z = g * acc[mi][nf][2] + xv.z;
        o.w = g * acc[mi][nf][3] + xv.w;
        *(float4*)&outp[ob] = o;
      } else {
        u16* outp = (u16*)outp_v;
        ushort4 o;
        o.x = f2h(acc[mi][nf][0]);
        o.y = f2h(acc[mi][nf][1]);
        o.z = f2h(acc[mi][nf][2]);
        o.w = f2h(acc[mi][nf][3]);
        *(ushort4*)&outp[ob] = o;
      }
    }
  }
}

// ---------------- launch ----------------
// ws (floats): Wp 40960+pad | q16,k16,q16T,k16T f16 4x8MB | stats 3MB | v,vT f16 2x64MB
// total = 42,811,776 f = 171.2 MB. accH aliases v (W out pass is last v reader).
extern "C" void kernel_launch(void* const* d_in, const int* in_sizes, int n_in,
                              void* d_out, int out_size, void* d_ws, size_t ws_size,
                              hipStream_t stream)
{
  const float* x1 = (const float*)d_in[0];
  const float* x2 = (const float*)d_in[1];
  const float* Wq = (const float*)d_in[2];
  const float* bq = (const float*)d_in[3];
  const float* Wk = (const float*)d_in[4];
  const float* bk = (const float*)d_in[5];
  const float* Wv = (const float*)d_in[6];
  const float* bv = (const float*)d_in[7];
  const float* gm = (const float*)d_in[8];
  float* out = (float*)d_out;
  float* ws = (float*)d_ws;

  u16*   Wp    = (u16*)ws;                  // 81,920 halfs
  float* ball  = ws + 81920;                // 320 f (region padded to 82,304)
  u16*   q16   = (u16*)(ws + 82304);        // 4,194,304 halfs each
  u16*   k16   = q16 + 4194304;
  u16*   q16T  = k16 + 4194304;
  u16*   k16T  = q16T + 4194304;
  float* stats = (float*)(k16T + 4194304);  // 786,432 f
  u16*   v     = (u16*)(stats + 786432);    // 33,554,432 halfs
  u16*   vT    = v + 33554432;              // 33,554,432 halfs
  u16*   accH  = v;                         // alias (v dead after W out pass)

  float* thrH = stats;
  float* mH   = stats + 131072;
  float* lH   = stats + 262144;
  float* thrW = stats + 393216;
  float* mW   = stats + 524288;
  float* lW   = stats + 655360;

  pack_kernel<<<320, 256, 0, stream>>>(Wq, bq, Wk, bk, Wv, bv, Wp, ball);
  proj_kernel<<<2048, 256, 0, stream>>>(x1, x2, Wp, ball, q16, k16, v);
  transpose_b16<<<dim3(16, 2048), 256, 0, stream>>>(v, vT);
  transpose_c32<<<dim3(64, 8), 256, 0, stream>>>(q16, q16T);
  transpose_c32<<<dim3(64, 8), 256, 0, stream>>>(k16, k16T);
  stats_kernel<<<dim3(128, 8), 256, 0, stream>>>(q16T, k16T, thrH, mH, lH, 1);
  stats_kernel<<<dim3(128, 8), 256, 0, stream>>>(q16, k16, thrW, mW, lW, 0);
  // W pass first (last reader of v), fused with gamma & +x1 into out:
  out_mfma<0, 1><<<dim3(128, 8), 512, 0, stream>>>(
      q16, k16, v, thrW, mW, lW, mH, lH, x1, gm, (void*)out);
  // H pass writes transposed accumulator (f16) into the now-dead v region:
  out_mfma<1, 0><<<dim3(128, 8), 512, 0, stream>>>(
      q16T, k16T, vT, thrH, mH, lH, mW, lW, x1, gm, (void*)accH);
  addT_kernel<<<dim3(16, 2048), 256, 0, stream>>>(accH, gm, out);
}